// Round 2
// baseline (1121.406 us; speedup 1.0000x reference)
//
#include <hip/hip_runtime.h>

typedef _Float16 f16;
typedef _Float16 f16x4 __attribute__((ext_vector_type(4)));
typedef _Float16 f16x8 __attribute__((ext_vector_type(8)));
typedef float    f32x4 __attribute__((ext_vector_type(4)));

#define MFMA(a,b,c) __builtin_amdgcn_mfma_f32_16x16x32_f16(a,b,c,0,0,0)

// ---------------------------------------------------------------------------
// f32 -> f16 elementwise convert
// ---------------------------------------------------------------------------
__global__ __launch_bounds__(256)
void tof16_kernel(const float* __restrict__ x, f16* __restrict__ y, int n4) {
  int i = blockIdx.x * 256 + threadIdx.x;
  if (i >= n4) return;
  f32x4 v = ((const f32x4*)x)[i];
  f16x4 h;
#pragma unroll
  for (int j = 0; j < 4; j++) h[j] = (f16)v[j];
  ((f16x4*)y)[i] = h;
}

// ---------------------------------------------------------------------------
// C = A(f32, converted to f16 at staging) * B(f16)^T ; K = 1024, lda/ldb = 1024
// MODE 0: C f16, ldc = 1024  (projection)
// MODE 1: C f32, ldc = 2048  (scores)
// 128x128 tile, BK=32, 4 waves x 4x4 fragments of mfma_f32_16x16x32_f16
// ---------------------------------------------------------------------------
template <int MODE>
__global__ __launch_bounds__(256)
void gemm_nt(const float* __restrict__ Ag, size_t sAz,
             const f16* __restrict__ Bg, size_t sBz,
             f16* __restrict__ Ch, float* __restrict__ Cf, size_t sCz) {
  __shared__ f16 Ah[128][40], Bh[128][40];
  const int tid = threadIdx.x;
  const size_t z = blockIdx.z;
  const float* A = Ag + z * sAz + (size_t)blockIdx.x * 128 * 1024;
  const f16* B = Bg + z * sBz + (size_t)blockIdx.y * 128 * 1024;

  f32x4 acc[4][4] = {};
  const int lane = tid & 63, w = tid >> 6;
  const int wr = w >> 1, wc = w & 1;
  const int lr = lane & 15, kg = lane >> 4, k0 = kg * 8;
  const int ar = tid >> 3, acg = (tid & 7) * 4;  // A: 8 thr/row * 4 f32
  const int br = tid >> 2, bg = (tid & 3) * 8;   // B: 4 thr/row * 8 f16 (FULL row)

  for (int kt = 0; kt < 1024; kt += 32) {
    // stage A tile (128x32 f32 -> f16), 4 passes of 32 rows
#pragma unroll
    for (int p = 0; p < 4; p++) {
      int r = ar + p * 32;
      f32x4 v = *(const f32x4*)(A + (size_t)r * 1024 + kt + acg);
      f16x4 h;
#pragma unroll
      for (int j = 0; j < 4; j++) h[j] = (f16)v[j];
      *(f16x4*)&Ah[r][acg] = h;
    }
    // stage B tile (128x32 f16), 2 passes of 64 rows, 4 thr/row x 8 halfs = 32
#pragma unroll
    for (int p = 0; p < 2; p++) {
      int r = br + p * 64;
      *(f16x8*)&Bh[r][bg] = *(const f16x8*)(B + (size_t)r * 1024 + kt + bg);
    }
    __syncthreads();

    f16x8 bf[4];
#pragma unroll
    for (int fn = 0; fn < 4; fn++)
      bf[fn] = *(const f16x8*)&Bh[wc * 64 + fn * 16 + lr][k0];
#pragma unroll
    for (int fm = 0; fm < 4; fm++) {
      f16x8 af = *(const f16x8*)&Ah[wr * 64 + fm * 16 + lr][k0];
#pragma unroll
      for (int fn = 0; fn < 4; fn++) acc[fm][fn] = MFMA(af, bf[fn], acc[fm][fn]);
    }
    __syncthreads();
  }

#pragma unroll
  for (int fm = 0; fm < 4; fm++)
#pragma unroll
    for (int fn = 0; fn < 4; fn++)
#pragma unroll
      for (int q = 0; q < 4; q++) {
        size_t grow = (size_t)blockIdx.x * 128 + wr * 64 + fm * 16 + kg * 4 + q;
        int gcol = blockIdx.y * 128 + wc * 64 + fn * 16 + lr;
        if (MODE == 0) {
          Ch[grow * 1024 + gcol] = (f16)acc[fm][fn][q];
        } else {
          Cf[z * sCz + grow * 2048 + gcol] = acc[fm][fn][q];
        }
      }
}

// ---------------------------------------------------------------------------
// O = P(f16, ldp = 2048) * V(f32 -> f16 at staging), K = 2048
// ---------------------------------------------------------------------------
__global__ __launch_bounds__(256)
void gemm_pv(const f16* __restrict__ Pg, size_t sPz,
             const float* __restrict__ Vg, size_t sVz,
             float* __restrict__ Og, size_t sOz) {
  __shared__ f16 Pl[128][40], Vl[128][40];
  const int tid = threadIdx.x;
  const size_t z = blockIdx.z;
  const f16* P = Pg + z * sPz + (size_t)blockIdx.x * 128 * 2048;
  const float* V = Vg + z * sVz + blockIdx.y * 128;
  float* O = Og + z * sOz + (size_t)blockIdx.x * 128 * 1024 + blockIdx.y * 128;

  f32x4 acc[4][4] = {};
  const int lane = tid & 63, w = tid >> 6;
  const int wr = w >> 1, wc = w & 1;
  const int lr = lane & 15, kg = lane >> 4, k0 = kg * 8;
  const int pr = tid >> 2, pg = (tid & 3) * 8;  // 4 thr/row x 8 halfs (FULL row)

  for (int kt = 0; kt < 2048; kt += 32) {
    // stage P tile 128x32 f16, 2 passes of 64 rows
#pragma unroll
    for (int p = 0; p < 2; p++) {
      int r = pr + p * 64;
      *(f16x8*)&Pl[r][pg] = *(const f16x8*)(P + (size_t)r * 2048 + kt + pg);
    }
    // stage V tile 32x128 f32 -> f16, transposed into Vl[col][k]
#pragma unroll
    for (int p = 0; p < 4; p++) {
      int idx = p * 256 + tid;
      int k = idx >> 5, cg = (idx & 31) * 4;
      f32x4 v = *(const f32x4*)(V + (size_t)(kt + k) * 1024 + cg);
#pragma unroll
      for (int j = 0; j < 4; j++) Vl[cg + j][k] = (f16)v[j];
    }
    __syncthreads();

    f16x8 vf[4];
#pragma unroll
    for (int fn = 0; fn < 4; fn++)
      vf[fn] = *(const f16x8*)&Vl[wc * 64 + fn * 16 + lr][k0];
#pragma unroll
    for (int fm = 0; fm < 4; fm++) {
      f16x8 pf = *(const f16x8*)&Pl[wr * 64 + fm * 16 + lr][k0];
#pragma unroll
      for (int fn = 0; fn < 4; fn++) acc[fm][fn] = MFMA(pf, vf[fn], acc[fm][fn]);
    }
    __syncthreads();
  }

#pragma unroll
  for (int fm = 0; fm < 4; fm++)
#pragma unroll
    for (int fn = 0; fn < 4; fn++)
#pragma unroll
      for (int q = 0; q < 4; q++) {
        O[(size_t)(wr * 64 + fm * 16 + kg * 4 + q) * 1024 + wc * 64 + fn * 16 + lr] =
            acc[fm][fn][q];
      }
}

// ---------------------------------------------------------------------------
// Row softmax: SC row (2048 f32) -> Pb row (2048 f16)
// ---------------------------------------------------------------------------
__global__ __launch_bounds__(256)
void softmax_rows(const float* __restrict__ SC, f16* __restrict__ Pb) {
  const float* r = SC + (size_t)blockIdx.x * 2048;
  f16* po = Pb + (size_t)blockIdx.x * 2048;
  const int tid = threadIdx.x;
  f32x4 a = *(const f32x4*)(r + tid * 8);
  f32x4 b = *(const f32x4*)(r + tid * 8 + 4);
  float x[8] = {a[0], a[1], a[2], a[3], b[0], b[1], b[2], b[3]};
  // sanitize: any NaN upstream becomes -1e30 (finite, diagnosable) not NaN
#pragma unroll
  for (int i = 0; i < 8; i++) x[i] = fminf(fmaxf(x[i], -1e30f), 1e30f);
  float m = x[0];
#pragma unroll
  for (int i = 1; i < 8; i++) m = fmaxf(m, x[i]);
#pragma unroll
  for (int off = 32; off; off >>= 1) m = fmaxf(m, __shfl_xor(m, off));
  __shared__ float rmax[4], rsum[4];
  const int w = tid >> 6, lane = tid & 63;
  if (!lane) rmax[w] = m;
  __syncthreads();
  m = fmaxf(fmaxf(rmax[0], rmax[1]), fmaxf(rmax[2], rmax[3]));
  float e[8], s = 0.f;
#pragma unroll
  for (int i = 0; i < 8; i++) {
    e[i] = __expf(x[i] - m);
    s += e[i];
  }
#pragma unroll
  for (int off = 32; off; off >>= 1) s += __shfl_xor(s, off);
  if (!lane) rsum[w] = s;
  __syncthreads();
  s = rsum[0] + rsum[1] + rsum[2] + rsum[3];
  float inv = 1.0f / s;
  f16x8 p;
#pragma unroll
  for (int i = 0; i < 8; i++) p[i] = (f16)(e[i] * inv);
  *(f16x8*)(po + tid * 8) = p;
}

// ---------------------------------------------------------------------------
extern "C" void kernel_launch(void* const* d_in, const int* in_sizes, int n_in,
                              void* d_out, int out_size, void* d_ws, size_t ws_size,
                              hipStream_t stream) {
  const float* S1 = (const float*)d_in[0];
  const float* S2 = (const float*)d_in[1];
  const float* W1 = (const float*)d_in[2];
  const float* W2 = (const float*)d_in[3];
  float* out = (float*)d_out;
  const int B = 8, N = 2048, H = 1024;
  const size_t NH = (size_t)N * H;  // 2M elems
  const size_t WN = (size_t)H * H;  // 1M elems

  char* ws = (char*)d_ws;
  f16* W1h = (f16*)ws;
  f16* W2h = W1h + WN;
  size_t fixed = 2 * WN * sizeof(f16);  // 4 MB
  // per-batch: Kh (NH f16 = 4MB) + SC (N*N f32 = 16MB) + Pb (N*N f16 = 8MB)
  size_t perb = NH * sizeof(f16) + (size_t)N * N * sizeof(float) +
                (size_t)N * N * sizeof(f16);  // 28 MB

  int bc = 1;
  const int cands[4] = {8, 4, 2, 1};
  for (int ci = 0; ci < 4; ci++) {
    if (fixed + (size_t)cands[ci] * perb <= ws_size) { bc = cands[ci]; break; }
  }
  f16* Kh = (f16*)(ws + fixed);
  float* SC = (float*)(Kh + (size_t)bc * NH);
  f16* Pb = (f16*)(SC + (size_t)bc * N * N);

  int n4 = (int)(WN / 4);
  tof16_kernel<<<dim3((n4 + 255) / 256), 256, 0, stream>>>(W1, W1h, n4);
  tof16_kernel<<<dim3((n4 + 255) / 256), 256, 0, stream>>>(W2, W2h, n4);

  for (int path = 0; path < 2; path++) {
    const float* Q = path ? S2 : S1;   // attention query side
    const float* X = path ? S1 : S2;   // proj input, also V
    const f16* Wh = path ? W2h : W1h;
    float* Op = out + (size_t)path * B * NH;
    for (int c0 = 0; c0 < B; c0 += bc) {
      // Kh = X @ W^T  (bc*N x 1024 f16)
      gemm_nt<0><<<dim3(bc * N / 128, H / 128, 1), 256, 0, stream>>>(
          X + (size_t)c0 * NH, 0, Wh, 0, Kh, nullptr, 0);
      // SC = Q @ Kh^T  (per batch 2048x2048 f32)
      gemm_nt<1><<<dim3(N / 128, N / 128, bc), 256, 0, stream>>>(
          Q + (size_t)c0 * NH, NH, Kh, NH, nullptr, SC, (size_t)N * N);
      // softmax rows -> Pb (f16)
      softmax_rows<<<dim3(bc * N), 256, 0, stream>>>(SC, Pb);
      // O = Pb @ V
      gemm_pv<<<dim3(N / 128, H / 128, bc), 256, 0, stream>>>(
          Pb, (size_t)N * N, X + (size_t)c0 * NH, NH, Op + (size_t)c0 * NH, NH);
    }
  }
}

// Round 3
// 777.205 us; speedup vs baseline: 1.4429x; 1.4429x over previous
//
#include <hip/hip_runtime.h>

typedef _Float16 f16;
typedef _Float16 f16x4 __attribute__((ext_vector_type(4)));
typedef _Float16 f16x8 __attribute__((ext_vector_type(8)));
typedef float    f32x4 __attribute__((ext_vector_type(4)));

#define MFMA(a,b,c) __builtin_amdgcn_mfma_f32_16x16x32_f16(a,b,c,0,0,0)

// async global->LDS, 16B per lane; lds dst must be wave-uniform base (+lane*16 by HW)
__device__ __forceinline__ void gload_lds16(const void* g, void* l) {
  __builtin_amdgcn_global_load_lds(
      (const __attribute__((address_space(1))) unsigned int*)g,
      (__attribute__((address_space(3))) unsigned int*)l, 16, 0, 0);
}

// ---------------------------------------------------------------------------
// f32 -> f16 elementwise convert
// ---------------------------------------------------------------------------
__global__ __launch_bounds__(256)
void tof16_kernel(const float* __restrict__ x, f16* __restrict__ y, int n4) {
  int i = blockIdx.x * 256 + threadIdx.x;
  if (i >= n4) return;
  f32x4 v = ((const f32x4*)x)[i];
  f16x4 h;
#pragma unroll
  for (int j = 0; j < 4; j++) h[j] = (f16)v[j];
  ((f16x4*)y)[i] = h;
}

// ---------------------------------------------------------------------------
// Transpose + convert: in f32 [z][2048][1024] -> out f16 [z][1024][2048]
// 64x64 tiles, LDS staged.
// ---------------------------------------------------------------------------
__global__ __launch_bounds__(256)
void transpose_f16_kernel(const float* __restrict__ in, f16* __restrict__ out) {
  __shared__ f16 t[64][68];
  const int tid = threadIdx.x;
  const size_t z = blockIdx.z;
  const int n0 = blockIdx.x * 64, h0 = blockIdx.y * 64;
  const int rr = tid >> 4, cc = (tid & 15) * 4;
#pragma unroll
  for (int p = 0; p < 4; p++) {
    int n = rr + p * 16;
    f32x4 v = *(const f32x4*)(in + ((size_t)z * 2048 + n0 + n) * 1024 + h0 + cc);
    f16x4 h;
#pragma unroll
    for (int j = 0; j < 4; j++) h[j] = (f16)v[j];
    *(f16x4*)&t[n][cc] = h;
  }
  __syncthreads();
#pragma unroll
  for (int p = 0; p < 4; p++) {
    int h = rr + p * 16;
    f16x4 o;
#pragma unroll
    for (int j = 0; j < 4; j++) o[j] = t[cc + j][h];
    *(f16x4*)(out + ((size_t)z * 1024 + h0 + h) * 2048 + n0 + cc) = o;
  }
}

// ---------------------------------------------------------------------------
// C = A(f16,[M][K] lda) * B(f16,[N][K] ldb)^T   (m97 structure)
// 128x128 tile, BK=32, 4 waves x 4x4 frags of mfma_f32_16x16x32_f16,
// linear LDS [128][32], global_load_lds width=16.
// OUTF32=0: C f16 ; OUTF32=1: C f32
// ---------------------------------------------------------------------------
template <int OUTF32>
__global__ __launch_bounds__(256)
void gemm_f16(const f16* __restrict__ Ag, size_t zA,
              const f16* __restrict__ Bg, size_t zB,
              void* __restrict__ Cg, size_t zC,
              int lda, int ldb, int ldc, int K) {
  __shared__ f16 As[128 * 32], Bs[128 * 32];
  const int tid = threadIdx.x;
  const size_t z = blockIdx.z;
  const f16* A = Ag + z * zA + (size_t)blockIdx.x * 128 * lda;
  const f16* B = Bg + z * zB + (size_t)blockIdx.y * 128 * ldb;

  const int lane = tid & 63, w = tid >> 6;
  const int wr = w >> 1, wc = w & 1;
  const int lr = lane & 15, kg = lane >> 4, k0 = kg * 8;
  const int srow = tid >> 2, scol = (tid & 3) * 8;  // 4 lanes/row * 8 halfs
  const int wbase = (tid & 192) * 8;                // wave-uniform LDS half-offset

  f32x4 acc[4][4] = {};

  for (int kt = 0; kt < K; kt += 32) {
    // stage A,B tiles (128x32 f16 each) via async global->LDS, 16B/lane
    gload_lds16(A + (size_t)srow * lda + kt + scol,        As + wbase);
    gload_lds16(A + (size_t)(srow + 64) * lda + kt + scol, As + 2048 + wbase);
    gload_lds16(B + (size_t)srow * ldb + kt + scol,        Bs + wbase);
    gload_lds16(B + (size_t)(srow + 64) * ldb + kt + scol, Bs + 2048 + wbase);
    __syncthreads();

    f16x8 bf[4];
#pragma unroll
    for (int fn = 0; fn < 4; fn++)
      bf[fn] = *(const f16x8*)&Bs[(wc * 64 + fn * 16 + lr) * 32 + k0];
#pragma unroll
    for (int fm = 0; fm < 4; fm++) {
      f16x8 af = *(const f16x8*)&As[(wr * 64 + fm * 16 + lr) * 32 + k0];
#pragma unroll
      for (int fn = 0; fn < 4; fn++) acc[fm][fn] = MFMA(af, bf[fn], acc[fm][fn]);
    }
    __syncthreads();
  }

#pragma unroll
  for (int fm = 0; fm < 4; fm++)
#pragma unroll
    for (int fn = 0; fn < 4; fn++)
#pragma unroll
      for (int q = 0; q < 4; q++) {
        size_t grow = (size_t)blockIdx.x * 128 + wr * 64 + fm * 16 + kg * 4 + q;
        int gcol = blockIdx.y * 128 + wc * 64 + fn * 16 + lr;
        if (OUTF32)
          ((float*)Cg)[z * zC + grow * ldc + gcol] = acc[fm][fn][q];
        else
          ((f16*)Cg)[z * zC + grow * ldc + gcol] = (f16)acc[fm][fn][q];
      }
}

// ---------------------------------------------------------------------------
// Row softmax: SC row (2048 f32) -> Pb row (2048 f16)
// ---------------------------------------------------------------------------
__global__ __launch_bounds__(256)
void softmax_rows(const float* __restrict__ SC, f16* __restrict__ Pb) {
  const float* r = SC + (size_t)blockIdx.x * 2048;
  f16* po = Pb + (size_t)blockIdx.x * 2048;
  const int tid = threadIdx.x;
  f32x4 a = *(const f32x4*)(r + tid * 8);
  f32x4 b = *(const f32x4*)(r + tid * 8 + 4);
  float x[8] = {a[0], a[1], a[2], a[3], b[0], b[1], b[2], b[3]};
#pragma unroll
  for (int i = 0; i < 8; i++) x[i] = fminf(fmaxf(x[i], -1e30f), 1e30f);
  float m = x[0];
#pragma unroll
  for (int i = 1; i < 8; i++) m = fmaxf(m, x[i]);
#pragma unroll
  for (int off = 32; off; off >>= 1) m = fmaxf(m, __shfl_xor(m, off));
  __shared__ float rmax[4], rsum[4];
  const int w = tid >> 6, lane = tid & 63;
  if (!lane) rmax[w] = m;
  __syncthreads();
  m = fmaxf(fmaxf(rmax[0], rmax[1]), fmaxf(rmax[2], rmax[3]));
  float e[8], s = 0.f;
#pragma unroll
  for (int i = 0; i < 8; i++) {
    e[i] = __expf(x[i] - m);
    s += e[i];
  }
#pragma unroll
  for (int off = 32; off; off >>= 1) s += __shfl_xor(s, off);
  if (!lane) rsum[w] = s;
  __syncthreads();
  s = rsum[0] + rsum[1] + rsum[2] + rsum[3];
  float inv = 1.0f / s;
  f16x8 p;
#pragma unroll
  for (int i = 0; i < 8; i++) p[i] = (f16)(e[i] * inv);
  *(f16x8*)(po + tid * 8) = p;
}

// ---------------------------------------------------------------------------
extern "C" void kernel_launch(void* const* d_in, const int* in_sizes, int n_in,
                              void* d_out, int out_size, void* d_ws, size_t ws_size,
                              hipStream_t stream) {
  const float* S1 = (const float*)d_in[0];
  const float* S2 = (const float*)d_in[1];
  const float* W1 = (const float*)d_in[2];
  const float* W2 = (const float*)d_in[3];
  float* out = (float*)d_out;
  const int B = 8, N = 2048, H = 1024;
  const size_t NH = (size_t)N * H;  // 2M elems
  const size_t WN = (size_t)H * H;  // 1M elems

  char* ws = (char*)d_ws;
  f16* W1h = (f16*)ws;
  f16* W2h = W1h + WN;
  size_t fixed = 2 * WN * sizeof(f16);  // 4 MB
  // per-batch: Ah+Bh+At+Bt+Kh (5*NH f16 = 20MB) + SC (16MB f32) + Pb (8MB f16)
  size_t perb = 5 * NH * sizeof(f16) + (size_t)N * N * sizeof(float) +
                (size_t)N * N * sizeof(f16);  // 44 MB

  int bc = 1;
  const int cands[4] = {8, 4, 2, 1};
  for (int ci = 0; ci < 4; ci++) {
    if (fixed + (size_t)cands[ci] * perb <= ws_size) { bc = cands[ci]; break; }
  }
  f16* Ah = (f16*)(ws + fixed);       // S1 chunk f16
  f16* Bh = Ah + (size_t)bc * NH;     // S2 chunk f16
  f16* At = Bh + (size_t)bc * NH;     // S1 chunk transposed f16 [z][1024][2048]
  f16* Bt = At + (size_t)bc * NH;     // S2 chunk transposed
  f16* Kh = Bt + (size_t)bc * NH;     // proj output
  float* SC = (float*)(Kh + (size_t)bc * NH);
  f16* Pb = (f16*)(SC + (size_t)bc * N * N);

  {
    int n4 = (int)(WN / 4);
    tof16_kernel<<<dim3((n4 + 255) / 256), 256, 0, stream>>>(W1, W1h, n4);
    tof16_kernel<<<dim3((n4 + 255) / 256), 256, 0, stream>>>(W2, W2h, n4);
  }

  for (int c0 = 0; c0 < B; c0 += bc) {
    // chunk conversions
    int n4 = (int)((size_t)bc * NH / 4);
    tof16_kernel<<<dim3((n4 + 255) / 256), 256, 0, stream>>>(S1 + (size_t)c0 * NH, Ah, n4);
    tof16_kernel<<<dim3((n4 + 255) / 256), 256, 0, stream>>>(S2 + (size_t)c0 * NH, Bh, n4);
    transpose_f16_kernel<<<dim3(N / 64, H / 64, bc), 256, 0, stream>>>(
        S1 + (size_t)c0 * NH, At);
    transpose_f16_kernel<<<dim3(N / 64, H / 64, bc), 256, 0, stream>>>(
        S2 + (size_t)c0 * NH, Bt);

    for (int path = 0; path < 2; path++) {
      const f16* Qh = path ? Bh : Ah;  // query side (f16)
      const f16* Xh = path ? Ah : Bh;  // proj input (f16)
      const f16* Vt = path ? At : Bt;  // V transposed [z][1024][2048]
      const f16* Wh = path ? W2h : W1h;
      float* Op = out + (size_t)path * B * NH + (size_t)c0 * NH;

      // Kh = Xh @ W^T : M = bc*2048 rows contiguous, N=1024, K=1024
      gemm_f16<0><<<dim3(bc * N / 128, H / 128, 1), 256, 0, stream>>>(
          Xh, 0, Wh, 0, Kh, 0, H, H, H, H);
      // SC = Qh @ Kh^T per batch: 2048x2048, K=1024
      gemm_f16<1><<<dim3(N / 128, N / 128, bc), 256, 0, stream>>>(
          Qh, NH, Kh, NH, SC, (size_t)N * N, H, H, N, H);
      // softmax rows -> Pb f16
      softmax_rows<<<dim3(bc * N), 256, 0, stream>>>(SC, Pb);
      // O = Pb @ Vt^T : per batch 2048x1024, K=2048
      gemm_f16<1><<<dim3(N / 128, H / 128, bc), 256, 0, stream>>>(
          Pb, (size_t)N * N, Vt, NH, Op, NH, N, N, H, N);
    }
  }
}

// Round 4
// 536.994 us; speedup vs baseline: 2.0883x; 1.4473x over previous
//
#include <hip/hip_runtime.h>

typedef _Float16 f16;
typedef _Float16 f16x4 __attribute__((ext_vector_type(4)));
typedef _Float16 f16x8 __attribute__((ext_vector_type(8)));
typedef float    f32x4 __attribute__((ext_vector_type(4)));

#define MFMA(a,b,c) __builtin_amdgcn_mfma_f32_16x16x32_f16(a,b,c,0,0,0)
#define SBAR() __builtin_amdgcn_sched_barrier(0)
#define BARRIER() do { SBAR(); __builtin_amdgcn_s_barrier(); SBAR(); } while (0)
#define VMCNT(n) do { SBAR(); asm volatile("s_waitcnt vmcnt(" #n ")" ::: "memory"); SBAR(); } while (0)

__device__ __forceinline__ void gload_lds16(const f16* g, f16* l) {
  __builtin_amdgcn_global_load_lds(
      (const __attribute__((address_space(1))) unsigned int*)g,
      (__attribute__((address_space(3))) unsigned int*)l, 16, 0, 0);
}

// ---------------------------------------------------------------------------
// f32 -> f16 elementwise convert
// ---------------------------------------------------------------------------
__global__ __launch_bounds__(256)
void tof16_kernel(const float* __restrict__ x, f16* __restrict__ y, int n4) {
  int i = blockIdx.x * 256 + threadIdx.x;
  if (i >= n4) return;
  f32x4 v = ((const f32x4*)x)[i];
  f16x4 h;
#pragma unroll
  for (int j = 0; j < 4; j++) h[j] = (f16)v[j];
  ((f16x4*)y)[i] = h;
}

// ---------------------------------------------------------------------------
// Transpose + convert: in f32 [z][2048][1024] -> out f16 [z][1024][2048]
// ---------------------------------------------------------------------------
__global__ __launch_bounds__(256)
void transpose_f16_kernel(const float* __restrict__ in, f16* __restrict__ out) {
  __shared__ f16 t[64][68];
  const int tid = threadIdx.x;
  const size_t z = blockIdx.z;
  const int n0 = blockIdx.x * 64, h0 = blockIdx.y * 64;
  const int rr = tid >> 4, cc = (tid & 15) * 4;
#pragma unroll
  for (int p = 0; p < 4; p++) {
    int n = rr + p * 16;
    f32x4 v = *(const f32x4*)(in + ((size_t)z * 2048 + n0 + n) * 1024 + h0 + cc);
    f16x4 h;
#pragma unroll
    for (int j = 0; j < 4; j++) h[j] = (f16)v[j];
    *(f16x4*)&t[n][cc] = h;
  }
  __syncthreads();
#pragma unroll
  for (int p = 0; p < 4; p++) {
    int h = rr + p * 16;
    f16x4 o;
#pragma unroll
    for (int j = 0; j < 4; j++) o[j] = t[cc + j][h];
    *(f16x4*)(out + ((size_t)z * 1024 + h0 + h) * 2048 + n0 + cc) = o;
  }
}

// ---------------------------------------------------------------------------
// 256x256-tile 8-phase GEMM:  C = A(f16,[M][K],lda) * B(f16,[N][K],ldb)^T
// BK=64 as two K-half units (256x32, 16KB, 2 x global_load_lds each),
// double-buffered LDS (128KB), 1 unit issued per phase, lead = 1 tile,
// counted vmcnt(6), raw barriers + sched_barrier fences, setprio on MFMA,
// XOR-swizzled units (chunk ^= (row>>1)&3) via pre-swizzled global source.
// 8 waves (2M x 4N), per-wave 128x64 output, 16 MFMA per phase.
// ---------------------------------------------------------------------------
template <int OUTF32>
__global__ __launch_bounds__(512, 2)
void gemm256(const f16* __restrict__ Ag, size_t zA,
             const f16* __restrict__ Bg, size_t zB,
             void* __restrict__ Cg, size_t zC,
             int lda, int ldb, int ldc, int K, int gx) {
  __shared__ f16 sm[8][8192];  // [c*4 + mat*2 + kk][256*32], 128 KB
  const int tid = threadIdx.x;
  const size_t z = blockIdx.z;
  int bx = blockIdx.x;
  { int qq = gx >> 3; bx = (bx & 7) * qq + (bx >> 3); }  // XCD swizzle (gx%8==0)
  const f16* A = Ag + z * zA + (size_t)bx * 256 * lda;
  const f16* B = Bg + z * zB + (size_t)blockIdx.y * 256 * ldb;

  const int lane = tid & 63, w = tid >> 6;
  const int wm = w >> 2, wn = w & 3;
  const int lr = lane & 15, kg = lane >> 4;
  const int sx = (kg ^ ((lr >> 1) & 3)) << 3;      // swizzled chunk for reads
  const int aoff = wm * 4096 + lr * 32 + sx;
  const int boff = wn * 2048 + lr * 32 + sx;
  const int colx = (((tid & 3) ^ ((tid >> 3) & 3)) << 3);  // pre-swizzled src col
  const int srow = tid >> 2;
  const int wls = w * 512;  // wave-uniform LDS base (halfs) per issue

  f32x4 acc[8][4] = {};
  f16x8 af[8], bf0, bf1;

#define STAGE(cc, mat, kkv, ktc) do {                                          \
    const f16* gs = ((mat) ? B : A) + (size_t)srow * ((mat) ? ldb : lda) +     \
                    (ktc) + (kkv) * 32 + colx;                                 \
    f16* ls = &sm[(cc) * 4 + (mat) * 2 + (kkv)][wls];                          \
    gload_lds16(gs, ls);                                                       \
    gload_lds16(gs + (size_t)128 * ((mat) ? ldb : lda), ls + 4096);            \
  } while (0)

#define LOAD_A(cc, kkv) do { _Pragma("unroll")                                 \
    for (int fm = 0; fm < 8; fm++)                                             \
      af[fm] = *(const f16x8*)&sm[(cc) * 4 + (kkv)][aoff + fm * 512];          \
  } while (0)

#define LOAD_B(cc, kkv, nh) do {                                               \
    bf0 = *(const f16x8*)&sm[(cc) * 4 + 2 + (kkv)][boff + (nh) * 1024];        \
    bf1 = *(const f16x8*)&sm[(cc) * 4 + 2 + (kkv)][boff + (nh) * 1024 + 512];  \
  } while (0)

#define DOMFMA(nh) do {                                                        \
    __builtin_amdgcn_s_setprio(1);                                             \
    _Pragma("unroll")                                                          \
    for (int fm = 0; fm < 8; fm++) {                                           \
      acc[fm][(nh) * 2]     = MFMA(af[fm], bf0, acc[fm][(nh) * 2]);            \
      acc[fm][(nh) * 2 + 1] = MFMA(af[fm], bf1, acc[fm][(nh) * 2 + 1]);        \
    }                                                                          \
    __builtin_amdgcn_s_setprio(0);                                             \
    SBAR();                                                                    \
  } while (0)

  const int nt = K >> 6;
  // prologue: stage tile 0 (units A0,B0,A1,B1) into buf 0
  STAGE(0, 0, 0, 0);
  STAGE(0, 1, 0, 0);
  STAGE(0, 0, 1, 0);
  STAGE(0, 1, 1, 0);

  for (int t = 0; t < nt - 1; ++t) {
    const int c = t & 1;
    const int kt1 = (t + 1) << 6;
    // phase 0: issue A0(t+1); need A0(t),B0(t): <=10 out, allow newest 3 units
    STAGE(c ^ 1, 0, 0, kt1);
    VMCNT(6);
    BARRIER();
    LOAD_A(c, 0); LOAD_B(c, 0, 0);
    DOMFMA(0);
    BARRIER();
    // phase 1: issue B0(t+1); reuse af (kk=0)
    STAGE(c ^ 1, 1, 0, kt1);
    BARRIER();
    LOAD_B(c, 0, 1);
    DOMFMA(1);
    BARRIER();
    // phase 2: issue A1(t+1); need A1(t),B1(t)
    STAGE(c ^ 1, 0, 1, kt1);
    VMCNT(6);
    BARRIER();
    LOAD_A(c, 1); LOAD_B(c, 1, 0);
    DOMFMA(0);
    BARRIER();
    // phase 3: issue B1(t+1)
    STAGE(c ^ 1, 1, 1, kt1);
    BARRIER();
    LOAD_B(c, 1, 1);
    DOMFMA(1);
    BARRIER();
  }
  {  // last tile: no issues; outstanding = its own 4 units at most
    const int c = (nt - 1) & 1;
    VMCNT(4);
    BARRIER();
    LOAD_A(c, 0); LOAD_B(c, 0, 0);
    DOMFMA(0);
    BARRIER();
    LOAD_B(c, 0, 1);
    DOMFMA(1);
    VMCNT(0);
    BARRIER();
    LOAD_A(c, 1); LOAD_B(c, 1, 0);
    DOMFMA(0);
    BARRIER();
    LOAD_B(c, 1, 1);
    DOMFMA(1);
  }

#pragma unroll
  for (int fm = 0; fm < 8; fm++)
#pragma unroll
    for (int fn = 0; fn < 4; fn++)
#pragma unroll
      for (int q = 0; q < 4; q++) {
        size_t grow = (size_t)bx * 256 + wm * 128 + fm * 16 + kg * 4 + q;
        int gcol = blockIdx.y * 256 + wn * 64 + fn * 16 + lr;
        if (OUTF32)
          ((float*)Cg)[z * zC + grow * ldc + gcol] = acc[fm][fn][q];
        else
          ((f16*)Cg)[z * zC + grow * ldc + gcol] = (f16)acc[fm][fn][q];
      }
#undef STAGE
#undef LOAD_A
#undef LOAD_B
#undef DOMFMA
}

// ---------------------------------------------------------------------------
// Row softmax: SC row (2048 f32) -> Pb row (2048 f16)
// ---------------------------------------------------------------------------
__global__ __launch_bounds__(256)
void softmax_rows(const float* __restrict__ SC, f16* __restrict__ Pb) {
  const float* r = SC + (size_t)blockIdx.x * 2048;
  f16* po = Pb + (size_t)blockIdx.x * 2048;
  const int tid = threadIdx.x;
  f32x4 a = *(const f32x4*)(r + tid * 8);
  f32x4 b = *(const f32x4*)(r + tid * 8 + 4);
  float x[8] = {a[0], a[1], a[2], a[3], b[0], b[1], b[2], b[3]};
#pragma unroll
  for (int i = 0; i < 8; i++) x[i] = fminf(fmaxf(x[i], -1e30f), 1e30f);
  float m = x[0];
#pragma unroll
  for (int i = 1; i < 8; i++) m = fmaxf(m, x[i]);
#pragma unroll
  for (int off = 32; off; off >>= 1) m = fmaxf(m, __shfl_xor(m, off));
  __shared__ float rmax[4], rsum[4];
  const int w = tid >> 6, lane = tid & 63;
  if (!lane) rmax[w] = m;
  __syncthreads();
  m = fmaxf(fmaxf(rmax[0], rmax[1]), fmaxf(rmax[2], rmax[3]));
  float e[8], s = 0.f;
#pragma unroll
  for (int i = 0; i < 8; i++) {
    e[i] = __expf(x[i] - m);
    s += e[i];
  }
#pragma unroll
  for (int off = 32; off; off >>= 1) s += __shfl_xor(s, off);
  if (!lane) rsum[w] = s;
  __syncthreads();
  s = rsum[0] + rsum[1] + rsum[2] + rsum[3];
  float inv = 1.0f / s;
  f16x8 p;
#pragma unroll
  for (int i = 0; i < 8; i++) p[i] = (f16)(e[i] * inv);
  *(f16x8*)(po + tid * 8) = p;
}

// ---------------------------------------------------------------------------
extern "C" void kernel_launch(void* const* d_in, const int* in_sizes, int n_in,
                              void* d_out, int out_size, void* d_ws, size_t ws_size,
                              hipStream_t stream) {
  const float* S1 = (const float*)d_in[0];
  const float* S2 = (const float*)d_in[1];
  const float* W1 = (const float*)d_in[2];
  const float* W2 = (const float*)d_in[3];
  float* out = (float*)d_out;
  const int B = 8, N = 2048, H = 1024;
  const size_t NH = (size_t)N * H;  // 2M elems
  const size_t WN = (size_t)H * H;  // 1M elems

  char* ws = (char*)d_ws;
  f16* W1h = (f16*)ws;
  f16* W2h = W1h + WN;
  size_t fixed = 2 * WN * sizeof(f16);  // 4 MB
  size_t perb = 5 * NH * sizeof(f16) + (size_t)N * N * sizeof(float) +
                (size_t)N * N * sizeof(f16);  // 44 MB

  int bc = 1;
  const int cands[4] = {8, 4, 2, 1};
  for (int ci = 0; ci < 4; ci++) {
    if (fixed + (size_t)cands[ci] * perb <= ws_size) { bc = cands[ci]; break; }
  }
  f16* Ah = (f16*)(ws + fixed);       // S1 chunk f16
  f16* Bh = Ah + (size_t)bc * NH;     // S2 chunk f16
  f16* At = Bh + (size_t)bc * NH;     // S1 chunk transposed f16 [z][1024][2048]
  f16* Bt = At + (size_t)bc * NH;     // S2 chunk transposed
  f16* Kh = Bt + (size_t)bc * NH;     // proj output
  float* SC = (float*)(Kh + (size_t)bc * NH);
  f16* Pb = (f16*)(SC + (size_t)bc * N * N);

  {
    int n4 = (int)(WN / 4);
    tof16_kernel<<<dim3((n4 + 255) / 256), 256, 0, stream>>>(W1, W1h, n4);
    tof16_kernel<<<dim3((n4 + 255) / 256), 256, 0, stream>>>(W2, W2h, n4);
  }

  for (int c0 = 0; c0 < B; c0 += bc) {
    int n4 = (int)((size_t)bc * NH / 4);
    tof16_kernel<<<dim3((n4 + 255) / 256), 256, 0, stream>>>(S1 + (size_t)c0 * NH, Ah, n4);
    tof16_kernel<<<dim3((n4 + 255) / 256), 256, 0, stream>>>(S2 + (size_t)c0 * NH, Bh, n4);
    transpose_f16_kernel<<<dim3(N / 64, H / 64, bc), 256, 0, stream>>>(
        S1 + (size_t)c0 * NH, At);
    transpose_f16_kernel<<<dim3(N / 64, H / 64, bc), 256, 0, stream>>>(
        S2 + (size_t)c0 * NH, Bt);

    for (int path = 0; path < 2; path++) {
      const f16* Qh = path ? Bh : Ah;  // query side (f16)
      const f16* Xh = path ? Ah : Bh;  // proj input (f16)
      const f16* Vt = path ? At : Bt;  // V transposed [z][1024][2048]
      const f16* Wh = path ? W2h : W1h;
      float* Op = out + (size_t)path * B * NH + (size_t)c0 * NH;

      // Kh = Xh @ W^T : M = bc*2048, N = 1024, K = 1024
      gemm256<0><<<dim3(bc * N / 256, H / 256, 1), 512, 0, stream>>>(
          Xh, 0, Wh, 0, Kh, 0, H, H, H, H, bc * N / 256);
      // SC = Qh @ Kh^T per batch: 2048x2048, K = 1024
      gemm256<1><<<dim3(N / 256, N / 256, bc), 512, 0, stream>>>(
          Qh, NH, Kh, NH, SC, (size_t)N * N, H, H, N, H, N / 256);
      // softmax rows -> Pb f16
      softmax_rows<<<dim3(bc * N), 256, 0, stream>>>(SC, Pb);
      // O = Pb @ Vt^T : per batch 2048x1024, K = 2048
      gemm256<1><<<dim3(N / 256, H / 256, bc), 512, 0, stream>>>(
          Pb, (size_t)N * N, Vt, NH, Op, NH, N, N, H, N, N / 256);
    }
  }
}

// Round 5
// 516.499 us; speedup vs baseline: 2.1712x; 1.0397x over previous
//
#include <hip/hip_runtime.h>

typedef _Float16 f16;
typedef _Float16 f16x4 __attribute__((ext_vector_type(4)));
typedef _Float16 f16x8 __attribute__((ext_vector_type(8)));
typedef float    f32x4 __attribute__((ext_vector_type(4)));

#define MFMA(a,b,c) __builtin_amdgcn_mfma_f32_16x16x32_f16(a,b,c,0,0,0)
#define SBAR() __builtin_amdgcn_sched_barrier(0)
#define BARRIER() do { SBAR(); __builtin_amdgcn_s_barrier(); SBAR(); } while (0)
#define VMCNT(n) do { SBAR(); asm volatile("s_waitcnt vmcnt(" #n ")" ::: "memory"); SBAR(); } while (0)
#define LGKM0() do { asm volatile("s_waitcnt lgkmcnt(0)" ::: "memory"); SBAR(); } while (0)

__device__ __forceinline__ void gload_lds16(const f16* g, f16* l) {
  __builtin_amdgcn_global_load_lds(
      (const __attribute__((address_space(1))) unsigned int*)g,
      (__attribute__((address_space(3))) unsigned int*)l, 16, 0, 0);
}

// ---------------------------------------------------------------------------
// f32 -> f16 elementwise convert (weights only)
// ---------------------------------------------------------------------------
__global__ __launch_bounds__(256)
void tof16_kernel(const float* __restrict__ x, f16* __restrict__ y, int n4) {
  int i = blockIdx.x * 256 + threadIdx.x;
  if (i >= n4) return;
  f32x4 v = ((const f32x4*)x)[i];
  f16x4 h;
#pragma unroll
  for (int j = 0; j < 4; j++) h[j] = (f16)v[j];
  ((f16x4*)y)[i] = h;
}

// ---------------------------------------------------------------------------
// Fused convert + transpose: in f32 [z][2048][1024]
//   -> rm f16 [z][2048][1024] (row-major)  and  tr f16 [z][1024][2048]
// 64x64 tiles; reads S once.
// ---------------------------------------------------------------------------
__global__ __launch_bounds__(256)
void prep_f16_kernel(const float* __restrict__ in, f16* __restrict__ rm,
                     f16* __restrict__ tr) {
  __shared__ f16 t[64][68];
  const int tid = threadIdx.x;
  const size_t z = blockIdx.z;
  const int n0 = blockIdx.x * 64, h0 = blockIdx.y * 64;
  const int rr = tid >> 4, cc = (tid & 15) * 4;
#pragma unroll
  for (int p = 0; p < 4; p++) {
    int n = rr + p * 16;
    f32x4 v = *(const f32x4*)(in + ((size_t)z * 2048 + n0 + n) * 1024 + h0 + cc);
    f16x4 h;
#pragma unroll
    for (int j = 0; j < 4; j++) h[j] = (f16)v[j];
    *(f16x4*)&t[n][cc] = h;
    *(f16x4*)(rm + ((size_t)z * 2048 + n0 + n) * 1024 + h0 + cc) = h;
  }
  __syncthreads();
#pragma unroll
  for (int p = 0; p < 4; p++) {
    int h = rr + p * 16;
    f16x4 o;
#pragma unroll
    for (int j = 0; j < 4; j++) o[j] = t[cc + j][h];
    *(f16x4*)(tr + ((size_t)z * 1024 + h0 + h) * 2048 + n0 + cc) = o;
  }
}

// ---------------------------------------------------------------------------
// 256x256-tile 8-phase GEMM:  C = A(f16,[M][K],lda) * B(f16,[N][K],ldb)^T
// m201 phase order: {vm-guarded ds_read (pre-barrier) | stage-issue |
//   s_barrier | lgkmcnt(0) | setprio+MFMA | s_barrier}.
// vmcnt(4) checkpoints at END of ph1/ph3 — one barrier ahead of the phase
// that reads the guarded unit (global_load_lds completion is per-wave but
// slices are read cross-wave, so checkpoint must precede a barrier).
// ---------------------------------------------------------------------------
template <int OUTF32>
__global__ __launch_bounds__(512, 2)
void gemm256(const f16* __restrict__ Ag, size_t zA,
             const f16* __restrict__ Bg, size_t zB,
             void* __restrict__ Cg, size_t zC,
             int lda, int ldb, int ldc, int K, int gx) {
  __shared__ f16 sm[8][8192];  // [c*4 + mat*2 + kk][256*32], 128 KB
  const int tid = threadIdx.x;
  const size_t z = blockIdx.z;
  int bx = blockIdx.x;
  { int qq = gx >> 3; bx = (bx & 7) * qq + (bx >> 3); }  // XCD swizzle (gx%8==0)
  const f16* A = Ag + z * zA + (size_t)bx * 256 * lda;
  const f16* B = Bg + z * zB + (size_t)blockIdx.y * 256 * ldb;

  const int lane = tid & 63, w = tid >> 6;
  const int wm = w >> 2, wn = w & 3;
  const int lr = lane & 15, kg = lane >> 4;
  const int sx = (kg ^ ((lr >> 1) & 3)) << 3;      // swizzled chunk for reads
  const int aoff = wm * 4096 + lr * 32 + sx;
  const int boff = wn * 2048 + lr * 32 + sx;
  const int colx = (((tid & 3) ^ ((tid >> 3) & 3)) << 3);  // pre-swizzled src col
  const int srow = tid >> 2;
  const int wls = w * 512;  // wave-uniform LDS base (halfs) per issue

  f32x4 acc[8][4] = {};
  f16x8 af[8], bf0, bf1;

#define STAGE(cc, mat, kkv, ktc) do {                                          \
    const f16* gs = ((mat) ? B : A) + (size_t)srow * ((mat) ? ldb : lda) +     \
                    (ktc) + (kkv) * 32 + colx;                                 \
    f16* ls = &sm[(cc) * 4 + (mat) * 2 + (kkv)][wls];                          \
    gload_lds16(gs, ls);                                                       \
    gload_lds16(gs + (size_t)128 * ((mat) ? ldb : lda), ls + 4096);            \
  } while (0)

#define LOAD_A(cc, kkv) do { _Pragma("unroll")                                 \
    for (int fm = 0; fm < 8; fm++)                                             \
      af[fm] = *(const f16x8*)&sm[(cc) * 4 + (kkv)][aoff + fm * 512];          \
  } while (0)

#define LOAD_B(cc, kkv, nh) do {                                               \
    bf0 = *(const f16x8*)&sm[(cc) * 4 + 2 + (kkv)][boff + (nh) * 1024];        \
    bf1 = *(const f16x8*)&sm[(cc) * 4 + 2 + (kkv)][boff + (nh) * 1024 + 512];  \
  } while (0)

#define DOMFMA(nh) do {                                                        \
    __builtin_amdgcn_s_setprio(1);                                             \
    _Pragma("unroll")                                                          \
    for (int fm = 0; fm < 8; fm++) {                                           \
      acc[fm][(nh) * 2]     = MFMA(af[fm], bf0, acc[fm][(nh) * 2]);            \
      acc[fm][(nh) * 2 + 1] = MFMA(af[fm], bf1, acc[fm][(nh) * 2 + 1]);        \
    }                                                                          \
    __builtin_amdgcn_s_setprio(0);                                             \
    SBAR();                                                                    \
  } while (0)

  const int nt = K >> 6;
  // prologue: stage tile 0 (units A0,B0,A1,B1) into buf 0; guard A0,B0
  STAGE(0, 0, 0, 0);
  STAGE(0, 1, 0, 0);
  STAGE(0, 0, 1, 0);
  STAGE(0, 1, 1, 0);
  VMCNT(4);
  BARRIER();

  for (int t = 0; t < nt - 1; ++t) {
    const int c = t & 1;
    const int kt1 = (t + 1) << 6;
    // ph0: reads A0(t),B0(t) [guarded at t-1.ph3 / prologue]
    LOAD_A(c, 0); LOAD_B(c, 0, 0);
    STAGE(c ^ 1, 0, 0, kt1);
    BARRIER();
    LGKM0();
    DOMFMA(0);
    BARRIER();
    // ph1: reads B0(t); checkpoint guards A1(t),B1(t) for ph2
    LOAD_B(c, 0, 1);
    STAGE(c ^ 1, 1, 0, kt1);
    BARRIER();
    LGKM0();
    DOMFMA(1);
    VMCNT(4);
    BARRIER();
    // ph2: reads A1(t),B1(t)
    LOAD_A(c, 1); LOAD_B(c, 1, 0);
    STAGE(c ^ 1, 0, 1, kt1);
    BARRIER();
    LGKM0();
    DOMFMA(0);
    BARRIER();
    // ph3: reads B1(t); checkpoint guards A0(t+1),B0(t+1) for next ph0
    LOAD_B(c, 1, 1);
    STAGE(c ^ 1, 1, 1, kt1);
    BARRIER();
    LGKM0();
    DOMFMA(1);
    VMCNT(4);
    BARRIER();
  }
  {  // last tile: no staging
    const int c = (nt - 1) & 1;
    LOAD_A(c, 0); LOAD_B(c, 0, 0);
    BARRIER();
    LGKM0();
    DOMFMA(0);
    BARRIER();
    LOAD_B(c, 0, 1);
    BARRIER();
    LGKM0();
    DOMFMA(1);
    VMCNT(0);
    BARRIER();
    LOAD_A(c, 1); LOAD_B(c, 1, 0);
    BARRIER();
    LGKM0();
    DOMFMA(0);
    BARRIER();
    LOAD_B(c, 1, 1);
    BARRIER();
    LGKM0();
    DOMFMA(1);
  }

#pragma unroll
  for (int fm = 0; fm < 8; fm++)
#pragma unroll
    for (int fn = 0; fn < 4; fn++)
#pragma unroll
      for (int q = 0; q < 4; q++) {
        size_t grow = (size_t)bx * 256 + wm * 128 + fm * 16 + kg * 4 + q;
        int gcol = blockIdx.y * 256 + wn * 64 + fn * 16 + lr;
        if (OUTF32)
          ((float*)Cg)[z * zC + grow * ldc + gcol] = acc[fm][fn][q];
        else
          ((f16*)Cg)[z * zC + grow * ldc + gcol] = (f16)acc[fm][fn][q];
      }
#undef STAGE
#undef LOAD_A
#undef LOAD_B
#undef DOMFMA
}

// ---------------------------------------------------------------------------
// Row softmax: SC row (2048 f32) -> Pb row (2048 f16)
// ---------------------------------------------------------------------------
__global__ __launch_bounds__(256)
void softmax_rows(const float* __restrict__ SC, f16* __restrict__ Pb) {
  const float* r = SC + (size_t)blockIdx.x * 2048;
  f16* po = Pb + (size_t)blockIdx.x * 2048;
  const int tid = threadIdx.x;
  f32x4 a = *(const f32x4*)(r + tid * 8);
  f32x4 b = *(const f32x4*)(r + tid * 8 + 4);
  float x[8] = {a[0], a[1], a[2], a[3], b[0], b[1], b[2], b[3]};
#pragma unroll
  for (int i = 0; i < 8; i++) x[i] = fminf(fmaxf(x[i], -1e30f), 1e30f);
  float m = x[0];
#pragma unroll
  for (int i = 1; i < 8; i++) m = fmaxf(m, x[i]);
#pragma unroll
  for (int off = 32; off; off >>= 1) m = fmaxf(m, __shfl_xor(m, off));
  __shared__ float rmax[4], rsum[4];
  const int w = tid >> 6, lane = tid & 63;
  if (!lane) rmax[w] = m;
  __syncthreads();
  m = fmaxf(fmaxf(rmax[0], rmax[1]), fmaxf(rmax[2], rmax[3]));
  float e[8], s = 0.f;
#pragma unroll
  for (int i = 0; i < 8; i++) {
    e[i] = __expf(x[i] - m);
    s += e[i];
  }
#pragma unroll
  for (int off = 32; off; off >>= 1) s += __shfl_xor(s, off);
  if (!lane) rsum[w] = s;
  __syncthreads();
  s = rsum[0] + rsum[1] + rsum[2] + rsum[3];
  float inv = 1.0f / s;
  f16x8 p;
#pragma unroll
  for (int i = 0; i < 8; i++) p[i] = (f16)(e[i] * inv);
  *(f16x8*)(po + tid * 8) = p;
}

// ---------------------------------------------------------------------------
extern "C" void kernel_launch(void* const* d_in, const int* in_sizes, int n_in,
                              void* d_out, int out_size, void* d_ws, size_t ws_size,
                              hipStream_t stream) {
  const float* S1 = (const float*)d_in[0];
  const float* S2 = (const float*)d_in[1];
  const float* W1 = (const float*)d_in[2];
  const float* W2 = (const float*)d_in[3];
  float* out = (float*)d_out;
  const int B = 8, N = 2048, H = 1024;
  const size_t NH = (size_t)N * H;  // 2M elems
  const size_t WN = (size_t)H * H;  // 1M elems

  char* ws = (char*)d_ws;
  f16* W1h = (f16*)ws;
  f16* W2h = W1h + WN;
  size_t fixed = 2 * WN * sizeof(f16);  // 4 MB
  size_t perb = 5 * NH * sizeof(f16) + (size_t)N * N * sizeof(float) +
                (size_t)N * N * sizeof(f16);  // 44 MB

  int bc = 1;
  const int cands[4] = {8, 4, 2, 1};
  for (int ci = 0; ci < 4; ci++) {
    if (fixed + (size_t)cands[ci] * perb <= ws_size) { bc = cands[ci]; break; }
  }
  f16* Ah = (f16*)(ws + fixed);       // S1 chunk f16
  f16* Bh = Ah + (size_t)bc * NH;     // S2 chunk f16
  f16* At = Bh + (size_t)bc * NH;     // S1 chunk transposed f16 [z][1024][2048]
  f16* Bt = At + (size_t)bc * NH;     // S2 chunk transposed
  f16* Kh = Bt + (size_t)bc * NH;     // proj output
  float* SC = (float*)(Kh + (size_t)bc * NH);
  f16* Pb = (f16*)(SC + (size_t)bc * N * N);

  {
    int n4 = (int)(WN / 4);
    tof16_kernel<<<dim3((n4 + 255) / 256), 256, 0, stream>>>(W1, W1h, n4);
    tof16_kernel<<<dim3((n4 + 255) / 256), 256, 0, stream>>>(W2, W2h, n4);
  }

  for (int c0 = 0; c0 < B; c0 += bc) {
    prep_f16_kernel<<<dim3(N / 64, H / 64, bc), 256, 0, stream>>>(
        S1 + (size_t)c0 * NH, Ah, At);
    prep_f16_kernel<<<dim3(N / 64, H / 64, bc), 256, 0, stream>>>(
        S2 + (size_t)c0 * NH, Bh, Bt);

    for (int path = 0; path < 2; path++) {
      const f16* Qh = path ? Bh : Ah;  // query side (f16)
      const f16* Xh = path ? Ah : Bh;  // proj input (f16)
      const f16* Vt = path ? At : Bt;  // V transposed [z][1024][2048]
      const f16* Wh = path ? W2h : W1h;
      float* Op = out + (size_t)path * B * NH + (size_t)c0 * NH;

      // Kh = Xh @ W^T : M = bc*2048, N = 1024, K = 1024
      gemm256<0><<<dim3(bc * N / 256, H / 256, 1), 512, 0, stream>>>(
          Xh, 0, Wh, 0, Kh, 0, H, H, H, H, bc * N / 256);
      // SC = Qh @ Kh^T per batch: 2048x2048, K = 1024
      gemm256<1><<<dim3(N / 256, N / 256, bc), 512, 0, stream>>>(
          Qh, NH, Kh, NH, SC, (size_t)N * N, H, H, N, H, N / 256);
      // softmax rows -> Pb f16
      softmax_rows<<<dim3(bc * N), 256, 0, stream>>>(SC, Pb);
      // O = Pb @ Vt^T : per batch 2048x1024, K = 2048
      gemm256<1><<<dim3(N / 256, H / 256, bc), 512, 0, stream>>>(
          Pb, (size_t)N * N, Vt, NH, Op, NH, N, N, H, N, N / 256);
    }
  }
}